// Round 1
// baseline (680.488 us; speedup 1.0000x reference)
//
#include <hip/hip_runtime.h>
#include <hip/hip_bf16.h>
#include <stdint.h>

typedef __bf16 bf16x8 __attribute__((ext_vector_type(8)));
typedef float f32x4 __attribute__((ext_vector_type(4)));

#define AS1 __attribute__((address_space(1)))
#define AS3 __attribute__((address_space(3)))

__device__ __forceinline__ unsigned short f2bf(float x) {
    union { float f; uint32_t u; } v; v.f = x;
    uint32_t r = v.u + 0x7fffu + ((v.u >> 16) & 1u);
    return (unsigned short)(r >> 16);
}

// ---------- fp32 -> bf16, 4 elems/thread ----------
__global__ void k_f2bf(const float* __restrict__ in, unsigned short* __restrict__ out, int n4) {
    int i = blockIdx.x * blockDim.x + threadIdx.x;
    if (i >= n4) return;
    float4 v = reinterpret_cast<const float4*>(in)[i];
    ushort4 o;
    o.x = f2bf(v.x); o.y = f2bf(v.y); o.z = f2bf(v.z); o.w = f2bf(v.w);
    reinterpret_cast<ushort4*>(out)[i] = o;
}

// ---------- NT GEMM: C[M,N] = A[M,K] * B[N,K]^T, bf16 in, TOUT out ----------
// m97 structure: 128x128 tile, BK=32, 4 waves (2x2), 16x16x32 MFMA, global_load_lds w=16.
template <typename TOUT>
__global__ __launch_bounds__(256) void k_gemm_bt(
    const unsigned short* __restrict__ A,
    const unsigned short* __restrict__ B,
    TOUT* __restrict__ C, int M, int N, int K)
{
    __shared__ unsigned short Alds[128 * 32];
    __shared__ unsigned short Blds[128 * 32];
    const int tid = threadIdx.x;
    const int lane = tid & 63;
    const int wv = tid >> 6;
    const int wm = wv >> 1, wn = wv & 1;
    const int fl = lane & 15, fg = lane >> 4;
    const int bm = blockIdx.x, bn = blockIdx.y;

    const int ch1 = wv * 64 + lane;       // chunks 0..255
    const int ch2 = ch1 + 256;            // chunks 256..511
    const unsigned short* a1 = A + (size_t)(bm * 128 + (ch1 >> 2)) * K + ((ch1 & 3) << 3);
    const unsigned short* a2 = A + (size_t)(bm * 128 + (ch2 >> 2)) * K + ((ch2 & 3) << 3);
    const unsigned short* b1 = B + (size_t)(bn * 128 + (ch1 >> 2)) * K + ((ch1 & 3) << 3);
    const unsigned short* b2 = B + (size_t)(bn * 128 + (ch2 >> 2)) * K + ((ch2 & 3) << 3);
    unsigned short* la1 = Alds + wv * 512;
    unsigned short* la2 = Alds + 2048 + wv * 512;
    unsigned short* lb1 = Blds + wv * 512;
    unsigned short* lb2 = Blds + 2048 + wv * 512;

    f32x4 acc[4][4];
#pragma unroll
    for (int m = 0; m < 4; ++m)
#pragma unroll
        for (int n = 0; n < 4; ++n) acc[m][n] = (f32x4){0.f, 0.f, 0.f, 0.f};

    for (int k0 = 0; k0 < K; k0 += 32) {
        __builtin_amdgcn_global_load_lds((const AS1 void*)(a1 + k0), (AS3 void*)la1, 16, 0, 0);
        __builtin_amdgcn_global_load_lds((const AS1 void*)(a2 + k0), (AS3 void*)la2, 16, 0, 0);
        __builtin_amdgcn_global_load_lds((const AS1 void*)(b1 + k0), (AS3 void*)lb1, 16, 0, 0);
        __builtin_amdgcn_global_load_lds((const AS1 void*)(b2 + k0), (AS3 void*)lb2, 16, 0, 0);
        __syncthreads();
        bf16x8 af[4], bfr[4];
#pragma unroll
        for (int m = 0; m < 4; ++m)
            af[m] = *reinterpret_cast<const bf16x8*>(Alds + (wm * 64 + m * 16 + fl) * 32 + fg * 8);
#pragma unroll
        for (int n = 0; n < 4; ++n)
            bfr[n] = *reinterpret_cast<const bf16x8*>(Blds + (wn * 64 + n * 16 + fl) * 32 + fg * 8);
#pragma unroll
        for (int m = 0; m < 4; ++m)
#pragma unroll
            for (int n = 0; n < 4; ++n)
                acc[m][n] = __builtin_amdgcn_mfma_f32_16x16x32_bf16(af[m], bfr[n], acc[m][n], 0, 0, 0);
        __syncthreads();
    }
#pragma unroll
    for (int m = 0; m < 4; ++m)
#pragma unroll
        for (int n = 0; n < 4; ++n)
#pragma unroll
            for (int r = 0; r < 4; ++r) {
                int row = bm * 128 + wm * 64 + m * 16 + fg * 4 + r;
                int col = bn * 128 + wn * 64 + n * 16 + fl;
                float v = acc[m][n][r];
                if constexpr (sizeof(TOUT) == 2)
                    ((unsigned short*)C)[(size_t)row * N + col] = f2bf(v);
                else
                    C[(size_t)row * N + col] = v;
            }
}

// ---------- V transpose: qkv[b,s, 4096 + h*128 + d] -> vT[b,h,d,s] ----------
__global__ void k_transpose_v(const unsigned short* __restrict__ qkv, unsigned short* __restrict__ vT) {
    __shared__ unsigned short t[32][33];
    const int bh = blockIdx.z;              // b*16+h
    const int b = bh >> 4, h = bh & 15;
    const int s0 = blockIdx.x * 32, d0 = blockIdx.y * 32;
    const int tx = threadIdx.x, ty = threadIdx.y;   // (32,8)
#pragma unroll
    for (int i = 0; i < 4; ++i) {
        int s = s0 + ty + i * 8;
        t[ty + i * 8][tx] = qkv[(size_t)(b * 2048 + s) * 6144 + 4096 + h * 128 + d0 + tx];
    }
    __syncthreads();
#pragma unroll
    for (int i = 0; i < 4; ++i) {
        int d = d0 + ty + i * 8;
        vT[((size_t)bh * 128 + d) * 2048 + s0 + tx] = t[tx][ty + i * 8];
    }
}

// ---------- causal flash attention ----------
// grid (S/64, B*nh), 256 thr. Wave w owns q rows [qt*64+16w, +16). KVBLK=32.
__global__ __launch_bounds__(256) void k_attn(
    const unsigned short* __restrict__ qkv, const unsigned short* __restrict__ vT,
    unsigned short* __restrict__ out)
{
    __shared__ unsigned short plds[4][512];   // per-wave 16x32 bf16 P tile (swizzled)
    const int tid = threadIdx.x, lane = tid & 63, wv = tid >> 6;
    const int fl = lane & 15, fg = lane >> 4;
    const int qt = blockIdx.x, bh = blockIdx.y;
    const int b = bh >> 4, h = bh & 15;
    const int q0 = qt * 64 + wv * 16;
    const size_t base = (size_t)b * 2048 * 6144 + (size_t)h * 128;
    const unsigned short* Kbase = qkv + base + 2048;
    const unsigned short* Vbase = vT + (size_t)bh * 128 * 2048;
    unsigned short* pw = plds[wv];

    bf16x8 qf[4];
#pragma unroll
    for (int kk = 0; kk < 4; ++kk)
        qf[kk] = *reinterpret_cast<const bf16x8*>(qkv + base + (size_t)(q0 + fl) * 6144 + kk * 32 + fg * 8);

    f32x4 acc[8];
#pragma unroll
    for (int nb = 0; nb < 8; ++nb) acc[nb] = (f32x4){0.f, 0.f, 0.f, 0.f};
    float m_r[4] = {-1e30f, -1e30f, -1e30f, -1e30f};
    float l_r[4] = {0.f, 0.f, 0.f, 0.f};
    const float sc = 0.08838834764831845f;   // 1/sqrt(128)

    for (int kv0 = 0; kv0 < q0 + 16; kv0 += 32) {
        f32x4 s[2];
        s[0] = (f32x4){0.f, 0.f, 0.f, 0.f};
        s[1] = (f32x4){0.f, 0.f, 0.f, 0.f};
#pragma unroll
        for (int n = 0; n < 2; ++n)
#pragma unroll
            for (int kk = 0; kk < 4; ++kk) {
                bf16x8 kf = *reinterpret_cast<const bf16x8*>(
                    Kbase + (size_t)(kv0 + n * 16 + fl) * 6144 + kk * 32 + fg * 8);
                s[n] = __builtin_amdgcn_mfma_f32_16x16x32_bf16(qf[kk], kf, s[n], 0, 0, 0);
            }
        float sv[2][4], mx[4];
#pragma unroll
        for (int r = 0; r < 4; ++r) {
            int qi = q0 + fg * 4 + r;
            float v0 = s[0][r] * sc; if (kv0 + fl > qi)      v0 = -1e30f;
            float v1 = s[1][r] * sc; if (kv0 + 16 + fl > qi) v1 = -1e30f;
            sv[0][r] = v0; sv[1][r] = v1;
            float mr = fmaxf(v0, v1);
            mr = fmaxf(mr, __shfl_xor(mr, 1));
            mr = fmaxf(mr, __shfl_xor(mr, 2));
            mr = fmaxf(mr, __shfl_xor(mr, 4));
            mr = fmaxf(mr, __shfl_xor(mr, 8));
            mx[r] = mr;
        }
#pragma unroll
        for (int r = 0; r < 4; ++r) {
            float mnew = fmaxf(m_r[r], mx[r]);
            float corr = __expf(m_r[r] - mnew);
            m_r[r] = mnew;
            l_r[r] *= corr;
#pragma unroll
            for (int nb = 0; nb < 8; ++nb) acc[nb][r] *= corr;
            float p0 = __expf(sv[0][r] - mnew);
            float p1 = __expf(sv[1][r] - mnew);
            int row = fg * 4 + r;
            int byte0 = (row * 64 + fl * 2) ^ ((row & 7) << 4);
            int byte1 = (row * 64 + (16 + fl) * 2) ^ ((row & 7) << 4);
            *(unsigned short*)((char*)pw + byte0) = f2bf(p0);
            *(unsigned short*)((char*)pw + byte1) = f2bf(p1);
            float ps = p0 + p1;
            ps += __shfl_xor(ps, 1);
            ps += __shfl_xor(ps, 2);
            ps += __shfl_xor(ps, 4);
            ps += __shfl_xor(ps, 8);
            l_r[r] += ps;
        }
        asm volatile("s_waitcnt lgkmcnt(0)" ::: "memory");
        bf16x8 pf = *reinterpret_cast<const bf16x8*>((char*)pw + ((fl * 64 + fg * 16) ^ ((fl & 7) << 4)));
#pragma unroll
        for (int nb = 0; nb < 8; ++nb) {
            bf16x8 vf = *reinterpret_cast<const bf16x8*>(
                Vbase + (size_t)(nb * 16 + fl) * 2048 + kv0 + fg * 8);
            acc[nb] = __builtin_amdgcn_mfma_f32_16x16x32_bf16(pf, vf, acc[nb], 0, 0, 0);
        }
    }
    float inv[4];
#pragma unroll
    for (int r = 0; r < 4; ++r) inv[r] = 1.0f / l_r[r];
#pragma unroll
    for (int nb = 0; nb < 8; ++nb)
#pragma unroll
        for (int r = 0; r < 4; ++r) {
            int row = q0 + fg * 4 + r;
            int col = h * 128 + nb * 16 + fl;
            out[(size_t)(b * 2048 + row) * 2048 + col] = f2bf(acc[nb][r] * inv[r]);
        }
}

extern "C" void kernel_launch(void* const* d_in, const int* in_sizes, int n_in,
                              void* d_out, int out_size, void* d_ws, size_t ws_size,
                              hipStream_t stream) {
    const float* hs   = (const float*)d_in[0];   // [2,2048,2048]
    const float* wqkv = (const float*)d_in[1];   // [6144,2048]
    const float* wo   = (const float*)d_in[2];   // [2048,2048]
    float* out = (float*)d_out;

    char* p = (char*)d_ws;
    unsigned short* Xb    = (unsigned short*)p; p += (size_t)4096 * 2048 * 2;
    unsigned short* Wqkvb = (unsigned short*)p; p += (size_t)6144 * 2048 * 2;
    unsigned short* Wob   = (unsigned short*)p; p += (size_t)2048 * 2048 * 2;
    unsigned short* QKV   = (unsigned short*)p; p += (size_t)4096 * 6144 * 2;
    unsigned short* VT    = (unsigned short*)p; p += (size_t)32 * 128 * 2048 * 2;
    unsigned short* ATTN  = (unsigned short*)p; p += (size_t)4096 * 2048 * 2;

    k_f2bf<<<8192, 256, 0, stream>>>(hs, Xb, 2097152);
    k_f2bf<<<12288, 256, 0, stream>>>(wqkv, Wqkvb, 3145728);
    k_f2bf<<<4096, 256, 0, stream>>>(wo, Wob, 1048576);
    k_gemm_bt<unsigned short><<<dim3(32, 48), 256, 0, stream>>>(Xb, Wqkvb, QKV, 4096, 6144, 2048);
    k_transpose_v<<<dim3(64, 4, 32), dim3(32, 8), 0, stream>>>(QKV, VT);
    k_attn<<<dim3(32, 32), 256, 0, stream>>>(QKV, VT, ATTN);
    k_gemm_bt<float><<<dim3(32, 16), 256, 0, stream>>>(ATTN, Wob, out, 4096, 2048, 2048);
}

// Round 2
// 356.561 us; speedup vs baseline: 1.9085x; 1.9085x over previous
//
#include <hip/hip_runtime.h>
#include <hip/hip_bf16.h>
#include <stdint.h>

typedef __bf16 bf16x8 __attribute__((ext_vector_type(8)));
typedef float f32x4 __attribute__((ext_vector_type(4)));

#define AS1 __attribute__((address_space(1)))
#define AS3 __attribute__((address_space(3)))

__device__ __forceinline__ unsigned short f2bf(float x) {
    union { float f; uint32_t u; } v; v.f = x;
    uint32_t r = v.u + 0x7fffu + ((v.u >> 16) & 1u);
    return (unsigned short)(r >> 16);
}

// ---------- fp32 -> bf16, 4 elems/thread ----------
__global__ void k_f2bf(const float* __restrict__ in, unsigned short* __restrict__ out, int n4) {
    int i = blockIdx.x * blockDim.x + threadIdx.x;
    if (i >= n4) return;
    float4 v = reinterpret_cast<const float4*>(in)[i];
    ushort4 o;
    o.x = f2bf(v.x); o.y = f2bf(v.y); o.z = f2bf(v.z); o.w = f2bf(v.w);
    reinterpret_cast<ushort4*>(out)[i] = o;
}

// ---------- NT GEMM: C[M,N] = A[M,K] * B[N,K]^T, bf16 in, TOUT out ----------
template <typename TOUT>
__global__ __launch_bounds__(256) void k_gemm_bt(
    const unsigned short* __restrict__ A,
    const unsigned short* __restrict__ B,
    TOUT* __restrict__ C, int M, int N, int K)
{
    __shared__ unsigned short Alds[128 * 32];
    __shared__ unsigned short Blds[128 * 32];
    const int tid = threadIdx.x;
    const int lane = tid & 63;
    const int wv = tid >> 6;
    const int wm = wv >> 1, wn = wv & 1;
    const int fl = lane & 15, fg = lane >> 4;
    const int bm = blockIdx.x, bn = blockIdx.y;

    const int ch1 = wv * 64 + lane;
    const int ch2 = ch1 + 256;
    const unsigned short* a1 = A + (size_t)(bm * 128 + (ch1 >> 2)) * K + ((ch1 & 3) << 3);
    const unsigned short* a2 = A + (size_t)(bm * 128 + (ch2 >> 2)) * K + ((ch2 & 3) << 3);
    const unsigned short* b1 = B + (size_t)(bn * 128 + (ch1 >> 2)) * K + ((ch1 & 3) << 3);
    const unsigned short* b2 = B + (size_t)(bn * 128 + (ch2 >> 2)) * K + ((ch2 & 3) << 3);
    unsigned short* la1 = Alds + wv * 512;
    unsigned short* la2 = Alds + 2048 + wv * 512;
    unsigned short* lb1 = Blds + wv * 512;
    unsigned short* lb2 = Blds + 2048 + wv * 512;

    f32x4 acc[4][4];
#pragma unroll
    for (int m = 0; m < 4; ++m)
#pragma unroll
        for (int n = 0; n < 4; ++n) acc[m][n] = (f32x4){0.f, 0.f, 0.f, 0.f};

    for (int k0 = 0; k0 < K; k0 += 32) {
        __builtin_amdgcn_global_load_lds((const AS1 void*)(a1 + k0), (AS3 void*)la1, 16, 0, 0);
        __builtin_amdgcn_global_load_lds((const AS1 void*)(a2 + k0), (AS3 void*)la2, 16, 0, 0);
        __builtin_amdgcn_global_load_lds((const AS1 void*)(b1 + k0), (AS3 void*)lb1, 16, 0, 0);
        __builtin_amdgcn_global_load_lds((const AS1 void*)(b2 + k0), (AS3 void*)lb2, 16, 0, 0);
        __syncthreads();
        bf16x8 af[4], bfr[4];
#pragma unroll
        for (int m = 0; m < 4; ++m)
            af[m] = *reinterpret_cast<const bf16x8*>(Alds + (wm * 64 + m * 16 + fl) * 32 + fg * 8);
#pragma unroll
        for (int n = 0; n < 4; ++n)
            bfr[n] = *reinterpret_cast<const bf16x8*>(Blds + (wn * 64 + n * 16 + fl) * 32 + fg * 8);
#pragma unroll
        for (int m = 0; m < 4; ++m)
#pragma unroll
            for (int n = 0; n < 4; ++n)
                acc[m][n] = __builtin_amdgcn_mfma_f32_16x16x32_bf16(af[m], bfr[n], acc[m][n], 0, 0, 0);
        __syncthreads();
    }
#pragma unroll
    for (int m = 0; m < 4; ++m)
#pragma unroll
        for (int n = 0; n < 4; ++n)
#pragma unroll
            for (int r = 0; r < 4; ++r) {
                int row = bm * 128 + wm * 64 + m * 16 + fg * 4 + r;
                int col = bn * 128 + wn * 64 + n * 16 + fl;
                float v = acc[m][n][r];
                if constexpr (sizeof(TOUT) == 2)
                    ((unsigned short*)C)[(size_t)row * N + col] = f2bf(v);
                else
                    C[(size_t)row * N + col] = v;
            }
}

// ---------- V transpose: qkv[b,s, 4096 + h*128 + d] -> vT[b,h,d,s] ----------
__global__ void k_transpose_v(const unsigned short* __restrict__ qkv, unsigned short* __restrict__ vT) {
    __shared__ unsigned short t[32][33];
    const int bh = blockIdx.z;
    const int b = bh >> 4, h = bh & 15;
    const int s0 = blockIdx.x * 32, d0 = blockIdx.y * 32;
    const int tx = threadIdx.x, ty = threadIdx.y;
#pragma unroll
    for (int i = 0; i < 4; ++i) {
        int s = s0 + ty + i * 8;
        t[ty + i * 8][tx] = qkv[(size_t)(b * 2048 + s) * 6144 + 4096 + h * 128 + d0 + tx];
    }
    __syncthreads();
#pragma unroll
    for (int i = 0; i < 4; ++i) {
        int d = d0 + ty + i * 8;
        vT[((size_t)bh * 128 + d) * 2048 + s0 + tx] = t[tx][ty + i * 8];
    }
}

// ---------- causal flash attention, LDS-staged double-buffered ----------
// grid (16, 32): qb = (bh>=16)? bx : 15-bx  (uniform-work pairing).
// 256 thr = 4 waves; wave owns 32 q rows [qb*128 + wv*32, +32). KVBLK=64.
// K LDS [64][128], VT LDS [128][64], P LDS per-wave [32][64]; all XOR-swizzled
// (byte ^= (row&7)<<4), staged linear with inverse-swizzled global source.
__global__ __launch_bounds__(256, 2) void k_attn(
    const unsigned short* __restrict__ qkv, const unsigned short* __restrict__ vT,
    unsigned short* __restrict__ out)
{
    __shared__ unsigned short Klds[2][8192];
    __shared__ unsigned short Vlds[2][8192];
    __shared__ unsigned short Plds[4][2048];

    const int tid = threadIdx.x, lane = tid & 63, wv = tid >> 6;
    const int fl = lane & 15, fg = lane >> 4;
    const int bh = blockIdx.y;
    const int qb = (bh >= 16) ? blockIdx.x : 15 - blockIdx.x;
    const int b = bh >> 4, h = bh & 15;
    const int q0w = qb * 128 + wv * 32;
    const size_t base = (size_t)b * 2048 * 6144 + (size_t)h * 128;
    const unsigned short* Qbase = qkv + base;
    const unsigned short* Kbase = qkv + base + 2048;
    const unsigned short* Vbase = vT + (size_t)bh * 128 * 2048;
    unsigned short* pw = Plds[wv];

    bf16x8 qf[2][4];
#pragma unroll
    for (int m = 0; m < 2; ++m)
#pragma unroll
        for (int kk = 0; kk < 4; ++kk)
            qf[m][kk] = *reinterpret_cast<const bf16x8*>(
                Qbase + (size_t)(q0w + m * 16 + fl) * 6144 + kk * 32 + fg * 8);

    f32x4 acc[2][8];
#pragma unroll
    for (int m = 0; m < 2; ++m)
#pragma unroll
        for (int nb = 0; nb < 8; ++nb) acc[m][nb] = (f32x4){0.f, 0.f, 0.f, 0.f};
    float m_r[2][4], l_r[2][4];
#pragma unroll
    for (int m = 0; m < 2; ++m)
#pragma unroll
        for (int r = 0; r < 4; ++r) { m_r[m][r] = -1e30f; l_r[m][r] = 0.f; }
    const float sc = 0.08838834764831845f;
    const int nIter = 2 * qb + 2;

    auto stage = [&](int buf, int kv0) {
#pragma unroll
        for (int rnd = 0; rnd < 4; ++rnd) {      // K: 1024 chunks of 16B
            int ch = rnd * 256 + tid;
            int row = ch >> 4;
            int cbl = ((ch & 15) << 4) ^ ((row & 7) << 4);
            const unsigned short* src = Kbase + (size_t)(kv0 + row) * 6144 + (cbl >> 1);
            __builtin_amdgcn_global_load_lds((const AS1 void*)src,
                (AS3 void*)((char*)&Klds[buf][0] + (rnd * 256 + wv * 64) * 16), 16, 0, 0);
        }
#pragma unroll
        for (int rnd = 0; rnd < 4; ++rnd) {      // V: 1024 chunks of 16B
            int ch = rnd * 256 + tid;
            int row = ch >> 3;
            int cbl = ((ch & 7) << 4) ^ ((row & 7) << 4);
            const unsigned short* src = Vbase + (size_t)row * 2048 + kv0 + (cbl >> 1);
            __builtin_amdgcn_global_load_lds((const AS1 void*)src,
                (AS3 void*)((char*)&Vlds[buf][0] + (rnd * 256 + wv * 64) * 16), 16, 0, 0);
        }
    };

    stage(0, 0);
    asm volatile("s_waitcnt vmcnt(0)" ::: "memory");
    __syncthreads();

    int cur = 0;
    for (int it = 0; it < nIter; ++it) {
        const int kv0 = it * 64;
        if (it + 1 < nIter) stage(cur ^ 1, kv0 + 64);

        if (kv0 <= q0w + 31) {
            const bool full = (kv0 + 63 <= q0w);
            const unsigned short* Kb = Klds[cur];
            const unsigned short* Vb = Vlds[cur];
            f32x4 s[2][4];
#pragma unroll
            for (int m = 0; m < 2; ++m)
#pragma unroll
                for (int n = 0; n < 4; ++n) s[m][n] = (f32x4){0.f, 0.f, 0.f, 0.f};
#pragma unroll
            for (int kk = 0; kk < 4; ++kk)
#pragma unroll
                for (int n = 0; n < 4; ++n) {
                    const int row = n * 16 + fl;
                    bf16x8 kf = *reinterpret_cast<const bf16x8*>(
                        (const char*)Kb + row * 256 + ((kk * 64 + fg * 16) ^ ((row & 7) << 4)));
                    s[0][n] = __builtin_amdgcn_mfma_f32_16x16x32_bf16(qf[0][kk], kf, s[0][n], 0, 0, 0);
                    s[1][n] = __builtin_amdgcn_mfma_f32_16x16x32_bf16(qf[1][kk], kf, s[1][n], 0, 0, 0);
                }
#pragma unroll
            for (int m = 0; m < 2; ++m)
#pragma unroll
                for (int r = 0; r < 4; ++r) {
                    const int lrow = m * 16 + fg * 4 + r;
                    const int qi = q0w + lrow;
                    float v0 = s[m][0][r] * sc, v1 = s[m][1][r] * sc,
                          v2 = s[m][2][r] * sc, v3 = s[m][3][r] * sc;
                    if (!full) {
                        if (kv0 +      fl > qi) v0 = -3e38f;
                        if (kv0 + 16 + fl > qi) v1 = -3e38f;
                        if (kv0 + 32 + fl > qi) v2 = -3e38f;
                        if (kv0 + 48 + fl > qi) v3 = -3e38f;
                    }
                    float mx = fmaxf(fmaxf(v0, v1), fmaxf(v2, v3));
                    mx = fmaxf(mx, __shfl_xor(mx, 1));
                    mx = fmaxf(mx, __shfl_xor(mx, 2));
                    mx = fmaxf(mx, __shfl_xor(mx, 4));
                    mx = fmaxf(mx, __shfl_xor(mx, 8));
                    float mnew = fmaxf(m_r[m][r], mx);
                    float corr = __expf(m_r[m][r] - mnew);
                    m_r[m][r] = mnew;
#pragma unroll
                    for (int nb = 0; nb < 8; ++nb) acc[m][nb][r] *= corr;
                    float p0 = __expf(v0 - mnew), p1 = __expf(v1 - mnew),
                          p2 = __expf(v2 - mnew), p3 = __expf(v3 - mnew);
                    const int rb = lrow * 128, sw = (lrow & 7) << 4;
                    *(unsigned short*)((char*)pw + rb + (( 0 + fl * 2) ^ sw)) = f2bf(p0);
                    *(unsigned short*)((char*)pw + rb + ((32 + fl * 2) ^ sw)) = f2bf(p1);
                    *(unsigned short*)((char*)pw + rb + ((64 + fl * 2) ^ sw)) = f2bf(p2);
                    *(unsigned short*)((char*)pw + rb + ((96 + fl * 2) ^ sw)) = f2bf(p3);
                    float ps = p0 + p1 + p2 + p3;
                    ps += __shfl_xor(ps, 1);
                    ps += __shfl_xor(ps, 2);
                    ps += __shfl_xor(ps, 4);
                    ps += __shfl_xor(ps, 8);
                    l_r[m][r] = l_r[m][r] * corr + ps;
                }
            asm volatile("s_waitcnt lgkmcnt(0)" ::: "memory");
            bf16x8 pf[2][2];
#pragma unroll
            for (int m = 0; m < 2; ++m)
#pragma unroll
                for (int k2 = 0; k2 < 2; ++k2) {
                    const int row = m * 16 + fl;
                    pf[m][k2] = *reinterpret_cast<const bf16x8*>(
                        (const char*)pw + row * 128 + ((k2 * 64 + fg * 16) ^ ((row & 7) << 4)));
                }
#pragma unroll
            for (int nb = 0; nb < 8; ++nb)
#pragma unroll
                for (int k2 = 0; k2 < 2; ++k2) {
                    const int d = nb * 16 + fl;
                    bf16x8 vf = *reinterpret_cast<const bf16x8*>(
                        (const char*)Vb + d * 128 + ((k2 * 64 + fg * 16) ^ ((d & 7) << 4)));
                    acc[0][nb] = __builtin_amdgcn_mfma_f32_16x16x32_bf16(pf[0][k2], vf, acc[0][nb], 0, 0, 0);
                    acc[1][nb] = __builtin_amdgcn_mfma_f32_16x16x32_bf16(pf[1][k2], vf, acc[1][nb], 0, 0, 0);
                }
        }
        asm volatile("s_waitcnt vmcnt(0)" ::: "memory");
        __syncthreads();
        cur ^= 1;
    }

#pragma unroll
    for (int m = 0; m < 2; ++m) {
        float inv[4];
#pragma unroll
        for (int r = 0; r < 4; ++r) inv[r] = 1.0f / l_r[m][r];
#pragma unroll
        for (int nb = 0; nb < 8; ++nb)
#pragma unroll
            for (int r = 0; r < 4; ++r) {
                int row = q0w + m * 16 + fg * 4 + r;
                int col = h * 128 + nb * 16 + fl;
                out[(size_t)(b * 2048 + row) * 2048 + col] = f2bf(acc[m][nb][r] * inv[r]);
            }
    }
}

extern "C" void kernel_launch(void* const* d_in, const int* in_sizes, int n_in,
                              void* d_out, int out_size, void* d_ws, size_t ws_size,
                              hipStream_t stream) {
    const float* hs   = (const float*)d_in[0];
    const float* wqkv = (const float*)d_in[1];
    const float* wo   = (const float*)d_in[2];
    float* out = (float*)d_out;

    char* p = (char*)d_ws;
    unsigned short* Xb    = (unsigned short*)p; p += (size_t)4096 * 2048 * 2;
    unsigned short* Wqkvb = (unsigned short*)p; p += (size_t)6144 * 2048 * 2;
    unsigned short* Wob   = (unsigned short*)p; p += (size_t)2048 * 2048 * 2;
    unsigned short* QKV   = (unsigned short*)p; p += (size_t)4096 * 6144 * 2;
    unsigned short* VT    = (unsigned short*)p; p += (size_t)32 * 128 * 2048 * 2;
    unsigned short* ATTN  = (unsigned short*)p; p += (size_t)4096 * 2048 * 2;

    k_f2bf<<<8192, 256, 0, stream>>>(hs, Xb, 2097152);
    k_f2bf<<<12288, 256, 0, stream>>>(wqkv, Wqkvb, 3145728);
    k_f2bf<<<4096, 256, 0, stream>>>(wo, Wob, 1048576);
    k_gemm_bt<unsigned short><<<dim3(32, 48), 256, 0, stream>>>(Xb, Wqkvb, QKV, 4096, 6144, 2048);
    k_transpose_v<<<dim3(64, 4, 32), dim3(32, 8), 0, stream>>>(QKV, VT);
    k_attn<<<dim3(16, 32), 256, 0, stream>>>(QKV, VT, ATTN);
    k_gemm_bt<float><<<dim3(32, 16), 256, 0, stream>>>(ATTN, Wob, out, 4096, 2048, 2048);
}

// Round 3
// 346.640 us; speedup vs baseline: 1.9631x; 1.0286x over previous
//
#include <hip/hip_runtime.h>
#include <hip/hip_bf16.h>
#include <stdint.h>

typedef __bf16 bf16x8 __attribute__((ext_vector_type(8)));
typedef float f32x4 __attribute__((ext_vector_type(4)));

#define AS1 __attribute__((address_space(1)))
#define AS3 __attribute__((address_space(3)))

#define PBAR() do { __builtin_amdgcn_sched_barrier(0); asm volatile("s_barrier" ::: "memory"); __builtin_amdgcn_sched_barrier(0); } while (0)
#define LGK0() do { asm volatile("s_waitcnt lgkmcnt(0)" ::: "memory"); __builtin_amdgcn_sched_barrier(0); } while (0)

__device__ __forceinline__ unsigned short f2bf(float x) {
    union { float f; uint32_t u; } v; v.f = x;
    uint32_t r = v.u + 0x7fffu + ((v.u >> 16) & 1u);
    return (unsigned short)(r >> 16);
}

// ---------- fp32 -> bf16, 4 elems/thread ----------
__global__ void k_f2bf(const float* __restrict__ in, unsigned short* __restrict__ out, int n4) {
    int i = blockIdx.x * blockDim.x + threadIdx.x;
    if (i >= n4) return;
    float4 v = reinterpret_cast<const float4*>(in)[i];
    ushort4 o;
    o.x = f2bf(v.x); o.y = f2bf(v.y); o.z = f2bf(v.z); o.w = f2bf(v.w);
    reinterpret_cast<ushort4*>(out)[i] = o;
}

// ---------- 256^2 8-wave 4-phase NT GEMM: C[M,N] = A[M,K]*B[N,K]^T (bf16 out) ----------
// BM=BN=256, BK=64, 512 thr (2Mx4N waves). T2 row-XOR swizzle, T3/T4 counted vmcnt(6),
// T5 setprio. Phase ledger: P1 reads A-mh0k0+Bk0, stages (t+1) A-mh1 -> buf^1;
// P2 reads A-mh1k0; P3 reads A-mh0k1+Bk1; P4 reads A-mh1k1, stages (t+2) A-mh0+B -> buf,
// then vmcnt(6) (tail: 0) + barrier. Regions staged only after their last reader's barrier.
__global__ __launch_bounds__(512, 2) void k_gemm256(
    const unsigned short* __restrict__ A,
    const unsigned short* __restrict__ B,
    unsigned short* __restrict__ C, int M, int N, int K)
{
    __shared__ __align__(16) unsigned short Albuf[2][16384];
    __shared__ __align__(16) unsigned short Blbuf[2][16384];
    const int tid = threadIdx.x, lane = tid & 63, wv = tid >> 6;
    const int wr = wv >> 2, wc = wv & 3;
    const int fl = lane & 15, fg = lane >> 4;
    const int bm = blockIdx.x, bn = blockIdx.y;
    const int nK = K >> 6;

    const unsigned short* Ag = A + (size_t)bm * 256 * K;
    const unsigned short* Bg = B + (size_t)bn * 256 * K;

    auto stage64 = [&](unsigned short* lds, const unsigned short* g) {
        const int row = tid >> 3;
        const unsigned short* src = g + (size_t)row * K + (((tid & 7) ^ (row & 7)) << 3);
        __builtin_amdgcn_global_load_lds((const AS1 void*)src,
            (AS3 void*)((char*)lds + wv * 1024), 16, 0, 0);
    };
    auto ldfrag = [&](const unsigned short* base, int row, int kk) -> bf16x8 {
        return *reinterpret_cast<const bf16x8*>(
            (const char*)base + row * 128 + ((kk * 64 + fg * 16) ^ ((row & 7) << 4)));
    };

    f32x4 acc[8][4];
#pragma unroll
    for (int i = 0; i < 8; ++i)
#pragma unroll
        for (int j = 0; j < 4; ++j) acc[i][j] = (f32x4){0.f, 0.f, 0.f, 0.f};

    // prologue: K-tile 0 fully into buf0; K-tile 1's A-mh0 + B into buf1
    stage64(&Albuf[0][0],     Ag);
    stage64(&Albuf[0][4096],  Ag + (size_t)64 * K);
    stage64(&Albuf[0][8192],  Ag + (size_t)128 * K);
    stage64(&Albuf[0][12288], Ag + (size_t)192 * K);
    stage64(&Blbuf[0][0],     Bg);
    stage64(&Blbuf[0][4096],  Bg + (size_t)64 * K);
    stage64(&Blbuf[0][8192],  Bg + (size_t)128 * K);
    stage64(&Blbuf[0][12288], Bg + (size_t)192 * K);
    stage64(&Albuf[1][0],     Ag + 64);
    stage64(&Albuf[1][8192],  Ag + (size_t)128 * K + 64);
    stage64(&Blbuf[1][0],     Bg + 64);
    stage64(&Blbuf[1][4096],  Bg + (size_t)64 * K + 64);
    stage64(&Blbuf[1][8192],  Bg + (size_t)128 * K + 64);
    stage64(&Blbuf[1][12288], Bg + (size_t)192 * K + 64);
    asm volatile("s_waitcnt vmcnt(6)" ::: "memory");
    PBAR();

    auto iter = [&](int t, int c) {
        const unsigned short* Ac = Albuf[c];
        const unsigned short* Bc = Blbuf[c];
        unsigned short* An = Albuf[c ^ 1];
        unsigned short* As = Albuf[c];
        unsigned short* Bs = Blbuf[c];
        bf16x8 af[4], bv[4];
        // ---- P1: (kk0, mh0) ----
#pragma unroll
        for (int i = 0; i < 4; ++i) af[i] = ldfrag(Ac, wr * 128 + i * 16 + fl, 0);
#pragma unroll
        for (int i = 0; i < 4; ++i) bv[i] = ldfrag(Bc, wc * 64 + i * 16 + fl, 0);
        if (t + 1 < nK) {
            stage64(An + 4096,  Ag + (size_t)64 * K  + (t + 1) * 64);
            stage64(An + 12288, Ag + (size_t)192 * K + (t + 1) * 64);
        }
        PBAR();
        LGK0();
        __builtin_amdgcn_s_setprio(1);
#pragma unroll
        for (int mf = 0; mf < 4; ++mf)
#pragma unroll
            for (int nf = 0; nf < 4; ++nf)
                acc[mf][nf] = __builtin_amdgcn_mfma_f32_16x16x32_bf16(af[mf], bv[nf], acc[mf][nf], 0, 0, 0);
        __builtin_amdgcn_s_setprio(0);
        PBAR();
        // ---- P2: (kk0, mh1) ----
#pragma unroll
        for (int i = 0; i < 4; ++i) af[i] = ldfrag(Ac, wr * 128 + 64 + i * 16 + fl, 0);
        PBAR();
        LGK0();
        __builtin_amdgcn_s_setprio(1);
#pragma unroll
        for (int mf = 0; mf < 4; ++mf)
#pragma unroll
            for (int nf = 0; nf < 4; ++nf)
                acc[4 + mf][nf] = __builtin_amdgcn_mfma_f32_16x16x32_bf16(af[mf], bv[nf], acc[4 + mf][nf], 0, 0, 0);
        __builtin_amdgcn_s_setprio(0);
        PBAR();
        // ---- P3: (kk1, mh0) ----
#pragma unroll
        for (int i = 0; i < 4; ++i) af[i] = ldfrag(Ac, wr * 128 + i * 16 + fl, 1);
#pragma unroll
        for (int i = 0; i < 4; ++i) bv[i] = ldfrag(Bc, wc * 64 + i * 16 + fl, 1);
        PBAR();
        LGK0();
        __builtin_amdgcn_s_setprio(1);
#pragma unroll
        for (int mf = 0; mf < 4; ++mf)
#pragma unroll
            for (int nf = 0; nf < 4; ++nf)
                acc[mf][nf] = __builtin_amdgcn_mfma_f32_16x16x32_bf16(af[mf], bv[nf], acc[mf][nf], 0, 0, 0);
        __builtin_amdgcn_s_setprio(0);
        PBAR();
        // ---- P4: (kk1, mh1) ----
#pragma unroll
        for (int i = 0; i < 4; ++i) af[i] = ldfrag(Ac, wr * 128 + 64 + i * 16 + fl, 1);
        if (t + 2 < nK) {
            stage64(As,         Ag + (size_t)(t + 2) * 64);
            stage64(As + 8192,  Ag + (size_t)128 * K + (t + 2) * 64);
            stage64(Bs,         Bg + (size_t)(t + 2) * 64);
            stage64(Bs + 4096,  Bg + (size_t)64 * K  + (t + 2) * 64);
            stage64(Bs + 8192,  Bg + (size_t)128 * K + (t + 2) * 64);
            stage64(Bs + 12288, Bg + (size_t)192 * K + (t + 2) * 64);
        }
        PBAR();
        LGK0();
        __builtin_amdgcn_s_setprio(1);
#pragma unroll
        for (int mf = 0; mf < 4; ++mf)
#pragma unroll
            for (int nf = 0; nf < 4; ++nf)
                acc[4 + mf][nf] = __builtin_amdgcn_mfma_f32_16x16x32_bf16(af[mf], bv[nf], acc[4 + mf][nf], 0, 0, 0);
        __builtin_amdgcn_s_setprio(0);
        if (t + 2 < nK) { asm volatile("s_waitcnt vmcnt(6)" ::: "memory"); }
        else            { asm volatile("s_waitcnt vmcnt(0)" ::: "memory"); }
        PBAR();
    };

    for (int tt = 0; tt < nK; tt += 2) {
        iter(tt, 0);
        iter(tt + 1, 1);
    }

#pragma unroll
    for (int am = 0; am < 8; ++am)
#pragma unroll
        for (int nf = 0; nf < 4; ++nf)
#pragma unroll
            for (int r = 0; r < 4; ++r) {
                int row = bm * 256 + wr * 128 + (am >> 2) * 64 + (am & 3) * 16 + fg * 4 + r;
                int col = bn * 256 + wc * 64 + nf * 16 + fl;
                C[(size_t)row * N + col] = f2bf(acc[am][nf][r]);
            }
}

// ---------- 128^2 NT GEMM (m97 structure) — used for O-proj ----------
template <typename TOUT>
__global__ __launch_bounds__(256) void k_gemm_bt(
    const unsigned short* __restrict__ A,
    const unsigned short* __restrict__ B,
    TOUT* __restrict__ C, int M, int N, int K)
{
    __shared__ unsigned short Alds[128 * 32];
    __shared__ unsigned short Blds[128 * 32];
    const int tid = threadIdx.x;
    const int lane = tid & 63;
    const int wv = tid >> 6;
    const int wm = wv >> 1, wn = wv & 1;
    const int fl = lane & 15, fg = lane >> 4;
    const int bm = blockIdx.x, bn = blockIdx.y;

    const int ch1 = wv * 64 + lane;
    const int ch2 = ch1 + 256;
    const unsigned short* a1 = A + (size_t)(bm * 128 + (ch1 >> 2)) * K + ((ch1 & 3) << 3);
    const unsigned short* a2 = A + (size_t)(bm * 128 + (ch2 >> 2)) * K + ((ch2 & 3) << 3);
    const unsigned short* b1 = B + (size_t)(bn * 128 + (ch1 >> 2)) * K + ((ch1 & 3) << 3);
    const unsigned short* b2 = B + (size_t)(bn * 128 + (ch2 >> 2)) * K + ((ch2 & 3) << 3);
    unsigned short* la1 = Alds + wv * 512;
    unsigned short* la2 = Alds + 2048 + wv * 512;
    unsigned short* lb1 = Blds + wv * 512;
    unsigned short* lb2 = Blds + 2048 + wv * 512;

    f32x4 acc[4][4];
#pragma unroll
    for (int m = 0; m < 4; ++m)
#pragma unroll
        for (int n = 0; n < 4; ++n) acc[m][n] = (f32x4){0.f, 0.f, 0.f, 0.f};

    for (int k0 = 0; k0 < K; k0 += 32) {
        __builtin_amdgcn_global_load_lds((const AS1 void*)(a1 + k0), (AS3 void*)la1, 16, 0, 0);
        __builtin_amdgcn_global_load_lds((const AS1 void*)(a2 + k0), (AS3 void*)la2, 16, 0, 0);
        __builtin_amdgcn_global_load_lds((const AS1 void*)(b1 + k0), (AS3 void*)lb1, 16, 0, 0);
        __builtin_amdgcn_global_load_lds((const AS1 void*)(b2 + k0), (AS3 void*)lb2, 16, 0, 0);
        __syncthreads();
        bf16x8 af[4], bfr[4];
#pragma unroll
        for (int m = 0; m < 4; ++m)
            af[m] = *reinterpret_cast<const bf16x8*>(Alds + (wm * 64 + m * 16 + fl) * 32 + fg * 8);
#pragma unroll
        for (int n = 0; n < 4; ++n)
            bfr[n] = *reinterpret_cast<const bf16x8*>(Blds + (wn * 64 + n * 16 + fl) * 32 + fg * 8);
#pragma unroll
        for (int m = 0; m < 4; ++m)
#pragma unroll
            for (int n = 0; n < 4; ++n)
                acc[m][n] = __builtin_amdgcn_mfma_f32_16x16x32_bf16(af[m], bfr[n], acc[m][n], 0, 0, 0);
        __syncthreads();
    }
#pragma unroll
    for (int m = 0; m < 4; ++m)
#pragma unroll
        for (int n = 0; n < 4; ++n)
#pragma unroll
            for (int r = 0; r < 4; ++r) {
                int row = bm * 128 + wm * 64 + m * 16 + fg * 4 + r;
                int col = bn * 128 + wn * 64 + n * 16 + fl;
                float v = acc[m][n][r];
                if constexpr (sizeof(TOUT) == 2)
                    ((unsigned short*)C)[(size_t)row * N + col] = f2bf(v);
                else
                    C[(size_t)row * N + col] = v;
            }
}

// ---------- V transpose: qkv[b,s, 4096 + h*128 + d] -> vT[b,h,d,s] ----------
__global__ void k_transpose_v(const unsigned short* __restrict__ qkv, unsigned short* __restrict__ vT) {
    __shared__ unsigned short t[32][33];
    const int bh = blockIdx.z;
    const int b = bh >> 4, h = bh & 15;
    const int s0 = blockIdx.x * 32, d0 = blockIdx.y * 32;
    const int tx = threadIdx.x, ty = threadIdx.y;
#pragma unroll
    for (int i = 0; i < 4; ++i) {
        int s = s0 + ty + i * 8;
        t[ty + i * 8][tx] = qkv[(size_t)(b * 2048 + s) * 6144 + 4096 + h * 128 + d0 + tx];
    }
    __syncthreads();
#pragma unroll
    for (int i = 0; i < 4; ++i) {
        int d = d0 + ty + i * 8;
        vT[((size_t)bh * 128 + d) * 2048 + s0 + tx] = t[tx][ty + i * 8];
    }
}

// ---------- causal flash attention, LDS-staged double-buffered ----------
__global__ __launch_bounds__(256, 2) void k_attn(
    const unsigned short* __restrict__ qkv, const unsigned short* __restrict__ vT,
    unsigned short* __restrict__ out)
{
    __shared__ unsigned short Klds[2][8192];
    __shared__ unsigned short Vlds[2][8192];
    __shared__ unsigned short Plds[4][2048];

    const int tid = threadIdx.x, lane = tid & 63, wv = tid >> 6;
    const int fl = lane & 15, fg = lane >> 4;
    const int bh = blockIdx.y;
    const int qb = (bh >= 16) ? blockIdx.x : 15 - blockIdx.x;
    const int b = bh >> 4, h = bh & 15;
    const int q0w = qb * 128 + wv * 32;
    const size_t base = (size_t)b * 2048 * 6144 + (size_t)h * 128;
    const unsigned short* Qbase = qkv + base;
    const unsigned short* Kbase = qkv + base + 2048;
    const unsigned short* Vbase = vT + (size_t)bh * 128 * 2048;
    unsigned short* pw = Plds[wv];

    bf16x8 qf[2][4];
#pragma unroll
    for (int m = 0; m < 2; ++m)
#pragma unroll
        for (int kk = 0; kk < 4; ++kk)
            qf[m][kk] = *reinterpret_cast<const bf16x8*>(
                Qbase + (size_t)(q0w + m * 16 + fl) * 6144 + kk * 32 + fg * 8);

    f32x4 acc[2][8];
#pragma unroll
    for (int m = 0; m < 2; ++m)
#pragma unroll
        for (int nb = 0; nb < 8; ++nb) acc[m][nb] = (f32x4){0.f, 0.f, 0.f, 0.f};
    float m_r[2][4], l_r[2][4];
#pragma unroll
    for (int m = 0; m < 2; ++m)
#pragma unroll
        for (int r = 0; r < 4; ++r) { m_r[m][r] = -1e30f; l_r[m][r] = 0.f; }
    const float sc = 0.08838834764831845f;
    const int nIter = 2 * qb + 2;

    auto stage = [&](int buf, int kv0) {
#pragma unroll
        for (int rnd = 0; rnd < 4; ++rnd) {
            int ch = rnd * 256 + tid;
            int row = ch >> 4;
            int cbl = ((ch & 15) << 4) ^ ((row & 7) << 4);
            const unsigned short* src = Kbase + (size_t)(kv0 + row) * 6144 + (cbl >> 1);
            __builtin_amdgcn_global_load_lds((const AS1 void*)src,
                (AS3 void*)((char*)&Klds[buf][0] + (rnd * 256 + wv * 64) * 16), 16, 0, 0);
        }
#pragma unroll
        for (int rnd = 0; rnd < 4; ++rnd) {
            int ch = rnd * 256 + tid;
            int row = ch >> 3;
            int cbl = ((ch & 7) << 4) ^ ((row & 7) << 4);
            const unsigned short* src = Vbase + (size_t)row * 2048 + kv0 + (cbl >> 1);
            __builtin_amdgcn_global_load_lds((const AS1 void*)src,
                (AS3 void*)((char*)&Vlds[buf][0] + (rnd * 256 + wv * 64) * 16), 16, 0, 0);
        }
    };

    stage(0, 0);
    asm volatile("s_waitcnt vmcnt(0)" ::: "memory");
    __syncthreads();

    int cur = 0;
    for (int it = 0; it < nIter; ++it) {
        const int kv0 = it * 64;
        if (it + 1 < nIter) stage(cur ^ 1, kv0 + 64);

        if (kv0 <= q0w + 31) {
            const bool full = (kv0 + 63 <= q0w);
            const unsigned short* Kb = Klds[cur];
            const unsigned short* Vb = Vlds[cur];
            f32x4 s[2][4];
#pragma unroll
            for (int m = 0; m < 2; ++m)
#pragma unroll
                for (int n = 0; n < 4; ++n) s[m][n] = (f32x4){0.f, 0.f, 0.f, 0.f};
#pragma unroll
            for (int kk = 0; kk < 4; ++kk)
#pragma unroll
                for (int n = 0; n < 4; ++n) {
                    const int row = n * 16 + fl;
                    bf16x8 kf = *reinterpret_cast<const bf16x8*>(
                        (const char*)Kb + row * 256 + ((kk * 64 + fg * 16) ^ ((row & 7) << 4)));
                    s[0][n] = __builtin_amdgcn_mfma_f32_16x16x32_bf16(qf[0][kk], kf, s[0][n], 0, 0, 0);
                    s[1][n] = __builtin_amdgcn_mfma_f32_16x16x32_bf16(qf[1][kk], kf, s[1][n], 0, 0, 0);
                }
#pragma unroll
            for (int m = 0; m < 2; ++m)
#pragma unroll
                for (int r = 0; r < 4; ++r) {
                    const int lrow = m * 16 + fg * 4 + r;
                    const int qi = q0w + lrow;
                    float v0 = s[m][0][r] * sc, v1 = s[m][1][r] * sc,
                          v2 = s[m][2][r] * sc, v3 = s[m][3][r] * sc;
                    if (!full) {
                        if (kv0 +      fl > qi) v0 = -3e38f;
                        if (kv0 + 16 + fl > qi) v1 = -3e38f;
                        if (kv0 + 32 + fl > qi) v2 = -3e38f;
                        if (kv0 + 48 + fl > qi) v3 = -3e38f;
                    }
                    float mx = fmaxf(fmaxf(v0, v1), fmaxf(v2, v3));
                    mx = fmaxf(mx, __shfl_xor(mx, 1));
                    mx = fmaxf(mx, __shfl_xor(mx, 2));
                    mx = fmaxf(mx, __shfl_xor(mx, 4));
                    mx = fmaxf(mx, __shfl_xor(mx, 8));
                    float mnew = fmaxf(m_r[m][r], mx);
                    float corr = __expf(m_r[m][r] - mnew);
                    m_r[m][r] = mnew;
#pragma unroll
                    for (int nb = 0; nb < 8; ++nb) acc[m][nb][r] *= corr;
                    float p0 = __expf(v0 - mnew), p1 = __expf(v1 - mnew),
                          p2 = __expf(v2 - mnew), p3 = __expf(v3 - mnew);
                    const int rb = lrow * 128, sw = (lrow & 7) << 4;
                    *(unsigned short*)((char*)pw + rb + (( 0 + fl * 2) ^ sw)) = f2bf(p0);
                    *(unsigned short*)((char*)pw + rb + ((32 + fl * 2) ^ sw)) = f2bf(p1);
                    *(unsigned short*)((char*)pw + rb + ((64 + fl * 2) ^ sw)) = f2bf(p2);
                    *(unsigned short*)((char*)pw + rb + ((96 + fl * 2) ^ sw)) = f2bf(p3);
                    float ps = p0 + p1 + p2 + p3;
                    ps += __shfl_xor(ps, 1);
                    ps += __shfl_xor(ps, 2);
                    ps += __shfl_xor(ps, 4);
                    ps += __shfl_xor(ps, 8);
                    l_r[m][r] = l_r[m][r] * corr + ps;
                }
            asm volatile("s_waitcnt lgkmcnt(0)" ::: "memory");
            bf16x8 pf[2][2];
#pragma unroll
            for (int m = 0; m < 2; ++m)
#pragma unroll
                for (int k2 = 0; k2 < 2; ++k2) {
                    const int row = m * 16 + fl;
                    pf[m][k2] = *reinterpret_cast<const bf16x8*>(
                        (const char*)pw + row * 128 + ((k2 * 64 + fg * 16) ^ ((row & 7) << 4)));
                }
#pragma unroll
            for (int nb = 0; nb < 8; ++nb)
#pragma unroll
                for (int k2 = 0; k2 < 2; ++k2) {
                    const int d = nb * 16 + fl;
                    bf16x8 vf = *reinterpret_cast<const bf16x8*>(
                        (const char*)Vb + d * 128 + ((k2 * 64 + fg * 16) ^ ((d & 7) << 4)));
                    acc[0][nb] = __builtin_amdgcn_mfma_f32_16x16x32_bf16(pf[0][k2], vf, acc[0][nb], 0, 0, 0);
                    acc[1][nb] = __builtin_amdgcn_mfma_f32_16x16x32_bf16(pf[1][k2], vf, acc[1][nb], 0, 0, 0);
                }
        }
        asm volatile("s_waitcnt vmcnt(0)" ::: "memory");
        __syncthreads();
        cur ^= 1;
    }

#pragma unroll
    for (int m = 0; m < 2; ++m) {
        float inv[4];
#pragma unroll
        for (int r = 0; r < 4; ++r) inv[r] = 1.0f / l_r[m][r];
#pragma unroll
        for (int nb = 0; nb < 8; ++nb)
#pragma unroll
            for (int r = 0; r < 4; ++r) {
                int row = q0w + m * 16 + fg * 4 + r;
                int col = h * 128 + nb * 16 + fl;
                out[(size_t)(b * 2048 + row) * 2048 + col] = f2bf(acc[m][nb][r] * inv[r]);
            }
    }
}

extern "C" void kernel_launch(void* const* d_in, const int* in_sizes, int n_in,
                              void* d_out, int out_size, void* d_ws, size_t ws_size,
                              hipStream_t stream) {
    const float* hs   = (const float*)d_in[0];
    const float* wqkv = (const float*)d_in[1];
    const float* wo   = (const float*)d_in[2];
    float* out = (float*)d_out;

    char* p = (char*)d_ws;
    unsigned short* Xb    = (unsigned short*)p; p += (size_t)4096 * 2048 * 2;
    unsigned short* Wqkvb = (unsigned short*)p; p += (size_t)6144 * 2048 * 2;
    unsigned short* Wob   = (unsigned short*)p; p += (size_t)2048 * 2048 * 2;
    unsigned short* QKV   = (unsigned short*)p; p += (size_t)4096 * 6144 * 2;
    unsigned short* VT    = (unsigned short*)p; p += (size_t)32 * 128 * 2048 * 2;
    unsigned short* ATTN  = (unsigned short*)p; p += (size_t)4096 * 2048 * 2;

    k_f2bf<<<8192, 256, 0, stream>>>(hs, Xb, 2097152);
    k_f2bf<<<12288, 256, 0, stream>>>(wqkv, Wqkvb, 3145728);
    k_f2bf<<<4096, 256, 0, stream>>>(wo, Wob, 1048576);
    k_gemm256<<<dim3(16, 24), 512, 0, stream>>>(Xb, Wqkvb, QKV, 4096, 6144, 2048);
    k_transpose_v<<<dim3(64, 4, 32), dim3(32, 8), 0, stream>>>(QKV, VT);
    k_attn<<<dim3(16, 32), 256, 0, stream>>>(QKV, VT, ATTN);
    k_gemm_bt<float><<<dim3(32, 16), 256, 0, stream>>>(ATTN, Wob, out, 4096, 2048, 2048);
}